// Round 3
// baseline (385.748 us; speedup 1.0000x reference)
//
#include <hip/hip_runtime.h>

#define NTOK 1600
#define BT_TOTAL 8
#define INNER 128
#define HD 32
#define NH 4
#define QDIM 256

// Diagnostic round: internal idempotent repeats to expose per-kernel cost.
#define REP_A 8
#define REP_O 8

typedef short short8 __attribute__((ext_vector_type(8)));
typedef short short4v __attribute__((ext_vector_type(4)));
typedef float f32x2 __attribute__((ext_vector_type(2)));
typedef float f32x4 __attribute__((ext_vector_type(4)));
typedef float f32x16 __attribute__((ext_vector_type(16)));
typedef unsigned uint2v __attribute__((ext_vector_type(2)));

__device__ inline short f2b(float x) {  // fp32 -> bf16, RNE-ish (scattered stores)
  union { float f; unsigned u; } v; v.f = x;
  unsigned r = (v.u + 0x7FFF + ((v.u >> 16) & 1)) >> 16;
  return (short)r;
}
// packed bf16 convert: lo16 = bf16(a), hi16 = bf16(b), RNE, single VALU op
__device__ inline unsigned cvtpk(float a, float b) {
  unsigned r;
  asm("v_cvt_pk_bf16_f32 %0, %1, %2" : "=v"(r) : "v"(a), "v"(b));
  return r;
}
// v_permlane32_swap_b32: block-transpose primitive.
// Exchanges a.row1 (lanes 32-63) with b.row0 (lanes 0-31):
//   a' = {lanes 0-31: a[0:31],  lanes 32-63: b[0:31]}
//   b' = {lanes 0-31: a[32:63], lanes 32-63: b[32:63]}
__device__ inline void pswap(unsigned &a, unsigned &b) {
  uint2v r = __builtin_amdgcn_permlane32_swap(a, b, false, false);
  a = r[0]; b = r[1];
}
// opaque pointer copy: blocks LICM/CSE across diagnostic repeat iterations
__device__ inline const short* launder_s(const short* p) {
  unsigned long long u = (unsigned long long)p;
  asm volatile("" : "+v"(u));
  return (const short*)u;
}
__device__ inline const float* launder_f(const float* p) {
  unsigned long long u = (unsigned long long)p;
  asm volatile("" : "+v"(u));
  return (const float*)u;
}
// LDS fragment load from 8B-aligned rows (stride 36 shorts): two b64 reads
__device__ inline short8 ldsfrag(const short* p) {
  short4v a = *(const short4v*)p;
  short4v b = *(const short4v*)(p + 4);
  short8 r;
  r[0] = a[0]; r[1] = a[1]; r[2] = a[2]; r[3] = a[3];
  r[4] = b[0]; r[5] = b[1]; r[6] = b[2]; r[7] = b[3];
  return r;
}
__device__ inline short8 mk8(unsigned a, unsigned b, unsigned c, unsigned d) {
  union { unsigned u[4]; short8 v; } t;
  t.u[0] = a; t.u[1] = b; t.u[2] = c; t.u[3] = d;
  return t.v;
}

// ---- fused QKV projection (MFMA), register-prefetched staging -------------
// which=0: Q (scaled by 1/sqrt(32)*log2(e), so attn uses exp2 directly)
//          token-major [bt][h][tok][32]
// which=1: K token-major [bt][h][tok][32]
// which=2: V d-major [bt][i][tok]
__global__ __launch_bounds__(256) void proj_fused(
    const float* __restrict__ query, const float* __restrict__ Wq,
    const float* __restrict__ key, const float* __restrict__ Wk,
    const float* __restrict__ value, const float* __restrict__ Wv,
    short* __restrict__ Qbf, short* __restrict__ Kbf,
    short* __restrict__ Vbf) {
  const int n0 = blockIdx.x * 64;
  const int which = blockIdx.y;
  const int bt = blockIdx.z;
  const int t = threadIdx.x;
  const int lane = t & 63, w = t >> 6;
  const int quad = lane >> 4, n16 = lane & 15;

  const float* X; const float* Wt; short* Y; int nchunk; float scl;
  if (which == 0) {
    X = query; Wt = Wq; Y = Qbf; nchunk = 8;
    scl = 0.17677669529663687f * 1.4426950408889634f;  // fold log2(e)
  } else if (which == 1) {
    X = key; Wt = Wk; Y = Kbf; nchunk = 4; scl = 1.0f;
  } else {
    X = value; Wt = Wv; Y = Vbf; nchunk = 4; scl = 1.0f;
  }
  const float* Xb = X + (size_t)bt * (nchunk * 32) * NTOK;

  __shared__ short Xs[64 * 36];   // [tok][d] bf16
  __shared__ short Ws[128 * 36];  // [i][d] bf16

  f32x4 acc[8];
#pragma unroll
  for (int i = 0; i < 8; ++i) acc[i] = (f32x4){0.f, 0.f, 0.f, 0.f};

  const int iw = t & 127, g = t >> 7;

  float xf0[4], xf1[4], wf0[8], wf1[8];
  auto loadX = [&](int cd) {
#pragma unroll
    for (int dp = 0; dp < 4; ++dp) {
      int dl = w * 8 + dp * 2;
      xf0[dp] = Xb[(size_t)(cd + dl) * NTOK + n0 + lane];
      xf1[dp] = Xb[(size_t)(cd + dl + 1) * NTOK + n0 + lane];
    }
  };
  auto loadW = [&](int cd) {
#pragma unroll
    for (int dp = 0; dp < 8; ++dp) {
      int dl = g * 16 + dp * 2;
      wf0[dp] = Wt[(size_t)(cd + dl) * INNER + iw];
      wf1[dp] = Wt[(size_t)(cd + dl + 1) * INNER + iw];
    }
  };
  loadX(0); loadW(0);

  for (int c = 0; c < nchunk; ++c) {
#pragma unroll
    for (int dp = 0; dp < 4; ++dp)
      *(unsigned*)&Xs[lane * 36 + w * 8 + dp * 2] = cvtpk(xf0[dp], xf1[dp]);
#pragma unroll
    for (int dp = 0; dp < 8; ++dp)
      *(unsigned*)&Ws[iw * 36 + g * 16 + dp * 2] = cvtpk(wf0[dp], wf1[dp]);
    __syncthreads();
    if (c + 1 < nchunk) { loadX((c + 1) * 32); loadW((c + 1) * 32); }
    if (which != 2) {
      short8 a[4], b[2];
#pragma unroll
      for (int tg = 0; tg < 4; ++tg)
        a[tg] = ldsfrag(&Xs[(tg * 16 + n16) * 36 + quad * 8]);
#pragma unroll
      for (int cg = 0; cg < 2; ++cg)
        b[cg] = ldsfrag(&Ws[(w * 32 + cg * 16 + n16) * 36 + quad * 8]);
#pragma unroll
      for (int tg = 0; tg < 4; ++tg)
#pragma unroll
        for (int cg = 0; cg < 2; ++cg)
          acc[tg * 2 + cg] = __builtin_amdgcn_mfma_f32_16x16x32_bf16(
              a[tg], b[cg], acc[tg * 2 + cg], 0, 0, 0);
    } else {
      short8 a[2], b[4];
#pragma unroll
      for (int ig = 0; ig < 2; ++ig)
        a[ig] = ldsfrag(&Ws[(w * 32 + ig * 16 + n16) * 36 + quad * 8]);
#pragma unroll
      for (int tg = 0; tg < 4; ++tg)
        b[tg] = ldsfrag(&Xs[(tg * 16 + n16) * 36 + quad * 8]);
#pragma unroll
      for (int ig = 0; ig < 2; ++ig)
#pragma unroll
        for (int tg = 0; tg < 4; ++tg)
          acc[ig * 4 + tg] = __builtin_amdgcn_mfma_f32_16x16x32_bf16(
              a[ig], b[tg], acc[ig * 4 + tg], 0, 0, 0);
    }
    __syncthreads();
  }

  if (which != 2) {
    short* Yb = Y + ((size_t)bt * NH + w) * NTOK * HD;
#pragma unroll
    for (int tg = 0; tg < 4; ++tg)
#pragma unroll
      for (int cg = 0; cg < 2; ++cg) {
        f32x4 a = acc[tg * 2 + cg];
#pragma unroll
        for (int r = 0; r < 4; ++r) {
          int tok = n0 + tg * 16 + quad * 4 + r;
          Yb[(size_t)tok * HD + cg * 16 + n16] = f2b(a[r] * scl);
        }
      }
  } else {
#pragma unroll
    for (int ig = 0; ig < 2; ++ig)
#pragma unroll
      for (int tg = 0; tg < 4; ++tg) {
        f32x4 a = acc[ig * 4 + tg];
#pragma unroll
        for (int r = 0; r < 4; ++r) {
          int irow = w * 32 + ig * 16 + quad * 4 + r;
          Y[((size_t)bt * INNER + irow) * NTOK + n0 + tg * 16 + n16] =
              f2b(a[r]);
        }
      }
  }
}

// ---- MFMA attention, 32x32 shape, in-register P transpose -----------------
// grid 1600: id>>5 = 32-q tile (50), id&31 = (bt,h). Wave w covers k-range
// (416/416/384/384). Per 32k chunk: S^T = K x Q (2x mfma_32x32x16),
// exp2 (log2e pre-folded into Q), v_cvt_pk_bf16_f32 pack, permlane32_swap
// cross-half exchange builds the PV B-operand in-register, O^T += V x P^T.
// DIAGNOSTIC: whole pipeline repeated REP_A times (idempotent, laundered).
__global__ __launch_bounds__(256, 5) void attn_mfma(
    const short* __restrict__ Qb, const short* __restrict__ Kb,
    const short* __restrict__ Vb, short* __restrict__ Obf) {
  const int id = blockIdx.x;
  const int qt = id >> 5;
  const int pair = id & 31;
  const int bt = pair >> 2, h = pair & 3;
  const int wave = threadIdx.x >> 6, lane = threadIdx.x & 63;
  const int lh = lane >> 5, q32 = lane & 31;
  const int q0 = qt * 32;
  const size_t btok = ((size_t)bt * NH + h) * NTOK;
  const size_t bd = ((size_t)bt * NH + h) * HD;

  __shared__ float Cb[2][17][64];  // 8.5 KB combine buffers

  const short* Qp = &Qb[(btok + q0 + q32) * HD + lh * 8];
  const short8 bq0 = *(const short8*)(Qp);
  const short8 bq1 = *(const short8*)(Qp + 16);

  const int kstart = wave * 416 - (wave == 3 ? 32 : 0);
  const int nch = 13 - (wave >> 1);
  const short* Kp0 = &Kb[(btok + kstart + q32) * HD + lh * 8];
  const short* Vp0 = &Vb[(bd + q32) * NTOK + kstart + lh * 8];

#pragma unroll 1
  for (int rep = 0; rep < REP_A; ++rep) {
    const short* Kp = launder_s(Kp0);
    const short* Vp = launder_s(Vp0);

    f32x16 o = {0.f, 0.f, 0.f, 0.f, 0.f, 0.f, 0.f, 0.f,
                0.f, 0.f, 0.f, 0.f, 0.f, 0.f, 0.f, 0.f};
    f32x2 ls2 = {0.f, 0.f};

    short8 ak0 = *(const short8*)(Kp);
    short8 ak1 = *(const short8*)(Kp + 16);
    short8 av0 = *(const short8*)(Vp);
    short8 av1 = *(const short8*)(Vp + 16);

    for (int i = 0; i < nch; ++i) {
      const int kn = (i + 1 < nch) ? (i + 1) * 32 : 0;
      short8 nk0 = *(const short8*)(Kp + (size_t)kn * HD);
      short8 nk1 = *(const short8*)(Kp + (size_t)kn * HD + 16);
      short8 nv0 = *(const short8*)(Vp + kn);
      short8 nv1 = *(const short8*)(Vp + kn + 16);

      __builtin_amdgcn_s_setprio(1);
      f32x16 s = __builtin_amdgcn_mfma_f32_32x32x16_bf16(
          ak0, bq0,
          (f32x16){0.f, 0.f, 0.f, 0.f, 0.f, 0.f, 0.f, 0.f,
                   0.f, 0.f, 0.f, 0.f, 0.f, 0.f, 0.f, 0.f},
          0, 0, 0);
      s = __builtin_amdgcn_mfma_f32_32x32x16_bf16(ak1, bq1, s, 0, 0, 0);
      __builtin_amdgcn_s_setprio(0);

      // exp2 + pack: reg r holds S^T[k][q], k = (r&3) + 8*(r>>2) + 4*lh
      unsigned Pd[8];
#pragma unroll
      for (int g = 0; g < 4; ++g) {
        float e0 = __builtin_amdgcn_exp2f(s[4 * g + 0]);
        float e1 = __builtin_amdgcn_exp2f(s[4 * g + 1]);
        float e2 = __builtin_amdgcn_exp2f(s[4 * g + 2]);
        float e3 = __builtin_amdgcn_exp2f(s[4 * g + 3]);
        ls2 += (f32x2){e0, e1};
        ls2 += (f32x2){e2, e3};
        Pd[2 * g + 0] = cvtpk(e0, e1);
        Pd[2 * g + 1] = cvtpk(e2, e3);
      }
      // cross-half exchange in-register. pswap(a,b): a.row1 <-> b.row0
      pswap(Pd[0], Pd[2]);
      pswap(Pd[1], Pd[3]);
      pswap(Pd[4], Pd[6]);
      pswap(Pd[5], Pd[7]);
      short8 pb0 = mk8(Pd[0], Pd[1], Pd[2], Pd[3]);
      short8 pb1 = mk8(Pd[4], Pd[5], Pd[6], Pd[7]);

      __builtin_amdgcn_s_setprio(1);
      o = __builtin_amdgcn_mfma_f32_32x32x16_bf16(av0, pb0, o, 0, 0, 0);
      o = __builtin_amdgcn_mfma_f32_32x32x16_bf16(av1, pb1, o, 0, 0, 0);
      __builtin_amdgcn_s_setprio(0);

      ak0 = nk0; ak1 = nk1; av0 = nv0; av1 = nv1;
    }

    float lsum = ls2[0] + ls2[1];
    lsum += __shfl_xor(lsum, 32);  // full row sum over both halves

    // two-stage combine across waves (8.5 KB LDS)
    auto dump = [&](int sidx) {
#pragma unroll
      for (int r = 0; r < 16; ++r) Cb[sidx][r][lane] = o[r];
      Cb[sidx][16][lane] = lsum;
    };
    auto accum = [&](int sidx) {
#pragma unroll
      for (int r = 0; r < 16; ++r) o[r] += Cb[sidx][r][lane];
      lsum += Cb[sidx][16][lane];
    };
    if (wave == 1) dump(0);
    if (wave == 3) dump(1);
    __syncthreads();
    if (wave == 0) accum(0);
    if (wave == 2) accum(1);
    __syncthreads();
    if (wave == 2) dump(0);
    __syncthreads();
    if (wave == 0) {
      accum(0);
      const float inv = 1.f / lsum;
      // O^T C-layout: col q = q32, row d = (r&3)+8*(r>>2)+4*lh
      short* Op =
          &Obf[((size_t)bt * NTOK + q0 + q32) * INNER + h * HD + lh * 4];
#pragma unroll
      for (int g = 0; g < 4; ++g) {
        unsigned d0 = cvtpk(o[4 * g + 0] * inv, o[4 * g + 1] * inv);
        unsigned d1 = cvtpk(o[4 * g + 2] * inv, o[4 * g + 3] * inv);
        *(uint2*)&Op[8 * g] = make_uint2(d0, d1);
      }
    }
    __syncthreads();  // protect Cb WAR across reps
  }
}

// ---- output projection (MFMA). grid (25, 4, 8): 64 tok x 64 dout tiles ----
// DIAGNOSTIC: repeated REP_O times (idempotent, laundered).
__global__ __launch_bounds__(256) void oproj_mfma(
    const short* __restrict__ Obf, const float* __restrict__ Wo,
    const float* __restrict__ bo, float* __restrict__ out) {
  const int tok0 = blockIdx.x * 64, d0 = blockIdx.y * 64;
  const int bt = blockIdx.z;
  const int t = threadIdx.x, lane = t & 63, w = t >> 6;
  const int quad = lane >> 4, n16 = lane & 15;
  __shared__ short Wos[64 * 36];  // [dout][i] bf16
  const int tok = tok0 + w * 16 + n16;  // always < 1600
  const short* Obf_b = &Obf[((size_t)bt * NTOK + tok) * INNER];

#pragma unroll 1
  for (int rep = 0; rep < REP_O; ++rep) {
    const short* Obr = launder_s(Obf_b);
    const float* Wor = launder_f(Wo);

    f32x4 acc[4];
#pragma unroll
    for (int i = 0; i < 4; ++i) acc[i] = (f32x4){0.f, 0.f, 0.f, 0.f};

    float wf0[4], wf1[4];
    short8 bfr;
    auto loadWo = [&](int c) {
#pragma unroll
      for (int dp = 0; dp < 4; ++dp) {
        int il = w * 8 + dp * 2;
        wf0[dp] = Wor[(size_t)(c * 32 + il) * QDIM + d0 + lane];
        wf1[dp] = Wor[(size_t)(c * 32 + il + 1) * QDIM + d0 + lane];
      }
    };
    auto loadB = [&](int c) {
      bfr = *(const short8*)&Obr[c * 32 + quad * 8];
    };
    loadWo(0); loadB(0);

    for (int c = 0; c < 4; ++c) {
#pragma unroll
      for (int dp = 0; dp < 4; ++dp)
        *(unsigned*)&Wos[lane * 36 + w * 8 + dp * 2] = cvtpk(wf0[dp], wf1[dp]);
      __syncthreads();
      short8 b0 = bfr;
      if (c < 3) { loadWo(c + 1); loadB(c + 1); }
#pragma unroll
      for (int ag = 0; ag < 4; ++ag) {
        short8 a = ldsfrag(&Wos[(ag * 16 + n16) * 36 + quad * 8]);
        acc[ag] =
            __builtin_amdgcn_mfma_f32_16x16x32_bf16(a, b0, acc[ag], 0, 0, 0);
      }
      __syncthreads();
    }

#pragma unroll
    for (int ag = 0; ag < 4; ++ag) {
      f32x4 a = acc[ag];
#pragma unroll
      for (int r = 0; r < 4; ++r) {
        int dout = d0 + ag * 16 + quad * 4 + r;
        out[((size_t)bt * QDIM + dout) * NTOK + tok] = a[r] + bo[dout];
      }
    }
  }
}

extern "C" void kernel_launch(void* const* d_in, const int* in_sizes, int n_in,
                              void* d_out, int out_size, void* d_ws,
                              size_t ws_size, hipStream_t stream) {
  const float* query = (const float*)d_in[0];
  const float* key = (const float*)d_in[1];
  const float* value = (const float*)d_in[2];
  const float* Wq = (const float*)d_in[3];
  const float* Wk = (const float*)d_in[4];
  const float* Wv = (const float*)d_in[5];
  const float* Wo = (const float*)d_in[6];
  const float* bo = (const float*)d_in[7];
  float* out = (float*)d_out;

  const size_t arr = (size_t)BT_TOTAL * INNER * NTOK;
  short* Qbf = (short*)d_ws;
  short* Kbf = Qbf + arr;
  short* Vbf = Kbf + arr;
  short* Obf = Vbf + arr;

  proj_fused<<<dim3(25, 3, BT_TOTAL), 256, 0, stream>>>(
      query, Wq, key, Wk, value, Wv, Qbf, Kbf, Vbf);
  attn_mfma<<<dim3(1600), 256, 0, stream>>>(Qbf, Kbf, Vbf, Obf);
  oproj_mfma<<<dim3(25, 4, BT_TOTAL), 256, 0, stream>>>(Obf, Wo, bo, out);
}

// Round 4
// 208.727 us; speedup vs baseline: 1.8481x; 1.8481x over previous
//
#include <hip/hip_runtime.h>

#define NTOK 1600
#define BT_TOTAL 8
#define INNER 128
#define HD 32
#define NH 4
#define QDIM 256

// Diagnostic round 2: isolate proj_fused cost (attn/oproj at production).
#define REP_P 8

typedef short short8 __attribute__((ext_vector_type(8)));
typedef short short4v __attribute__((ext_vector_type(4)));
typedef float f32x2 __attribute__((ext_vector_type(2)));
typedef float f32x4 __attribute__((ext_vector_type(4)));
typedef float f32x16 __attribute__((ext_vector_type(16)));
typedef unsigned uint2v __attribute__((ext_vector_type(2)));

__device__ inline short f2b(float x) {  // fp32 -> bf16, RNE-ish (scattered stores)
  union { float f; unsigned u; } v; v.f = x;
  unsigned r = (v.u + 0x7FFF + ((v.u >> 16) & 1)) >> 16;
  return (short)r;
}
// packed bf16 convert: lo16 = bf16(a), hi16 = bf16(b), RNE, single VALU op
__device__ inline unsigned cvtpk(float a, float b) {
  unsigned r;
  asm("v_cvt_pk_bf16_f32 %0, %1, %2" : "=v"(r) : "v"(a), "v"(b));
  return r;
}
// v_permlane32_swap_b32: block-transpose primitive.
// Exchanges a.row1 (lanes 32-63) with b.row0 (lanes 0-31):
//   a' = {lanes 0-31: a[0:31],  lanes 32-63: b[0:31]}
//   b' = {lanes 0-31: a[32:63], lanes 32-63: b[32:63]}
__device__ inline void pswap(unsigned &a, unsigned &b) {
  uint2v r = __builtin_amdgcn_permlane32_swap(a, b, false, false);
  a = r[0]; b = r[1];
}
// opaque pointer copy: blocks LICM/CSE across diagnostic repeat iterations
__device__ inline const float* launder_f(const float* p) {
  unsigned long long u = (unsigned long long)p;
  asm volatile("" : "+v"(u));
  return (const float*)u;
}
// LDS fragment load from 8B-aligned rows (stride 36 shorts): two b64 reads
__device__ inline short8 ldsfrag(const short* p) {
  short4v a = *(const short4v*)p;
  short4v b = *(const short4v*)(p + 4);
  short8 r;
  r[0] = a[0]; r[1] = a[1]; r[2] = a[2]; r[3] = a[3];
  r[4] = b[0]; r[5] = b[1]; r[6] = b[2]; r[7] = b[3];
  return r;
}
__device__ inline short8 mk8(unsigned a, unsigned b, unsigned c, unsigned d) {
  union { unsigned u[4]; short8 v; } t;
  t.u[0] = a; t.u[1] = b; t.u[2] = c; t.u[3] = d;
  return t.v;
}

// ---- fused QKV projection (MFMA), register-prefetched staging -------------
// which=0: Q (scaled by 1/sqrt(32)*log2(e), so attn uses exp2 directly)
//          token-major [bt][h][tok][32]
// which=1: K token-major [bt][h][tok][32]
// which=2: V d-major [bt][i][tok]
// DIAGNOSTIC: whole body repeated REP_P times (idempotent, laundered).
__global__ __launch_bounds__(256) void proj_fused(
    const float* __restrict__ query, const float* __restrict__ Wq,
    const float* __restrict__ key, const float* __restrict__ Wk,
    const float* __restrict__ value, const float* __restrict__ Wv,
    short* __restrict__ Qbf, short* __restrict__ Kbf,
    short* __restrict__ Vbf) {
  const int n0 = blockIdx.x * 64;
  const int which = blockIdx.y;
  const int bt = blockIdx.z;
  const int t = threadIdx.x;
  const int lane = t & 63, w = t >> 6;
  const int quad = lane >> 4, n16 = lane & 15;

  const float* X; const float* Wt; short* Y; int nchunk; float scl;
  if (which == 0) {
    X = query; Wt = Wq; Y = Qbf; nchunk = 8;
    scl = 0.17677669529663687f * 1.4426950408889634f;  // fold log2(e)
  } else if (which == 1) {
    X = key; Wt = Wk; Y = Kbf; nchunk = 4; scl = 1.0f;
  } else {
    X = value; Wt = Wv; Y = Vbf; nchunk = 4; scl = 1.0f;
  }
  const float* Xb0 = X + (size_t)bt * (nchunk * 32) * NTOK;

  __shared__ short Xs[64 * 36];   // [tok][d] bf16
  __shared__ short Ws[128 * 36];  // [i][d] bf16

  const int iw = t & 127, g = t >> 7;

#pragma unroll 1
  for (int rep = 0; rep < REP_P; ++rep) {
    const float* Xb = launder_f(Xb0);
    const float* Wr = launder_f(Wt);

    f32x4 acc[8];
#pragma unroll
    for (int i = 0; i < 8; ++i) acc[i] = (f32x4){0.f, 0.f, 0.f, 0.f};

    float xf0[4], xf1[4], wf0[8], wf1[8];
    auto loadX = [&](int cd) {
#pragma unroll
      for (int dp = 0; dp < 4; ++dp) {
        int dl = w * 8 + dp * 2;
        xf0[dp] = Xb[(size_t)(cd + dl) * NTOK + n0 + lane];
        xf1[dp] = Xb[(size_t)(cd + dl + 1) * NTOK + n0 + lane];
      }
    };
    auto loadW = [&](int cd) {
#pragma unroll
      for (int dp = 0; dp < 8; ++dp) {
        int dl = g * 16 + dp * 2;
        wf0[dp] = Wr[(size_t)(cd + dl) * INNER + iw];
        wf1[dp] = Wr[(size_t)(cd + dl + 1) * INNER + iw];
      }
    };
    loadX(0); loadW(0);

    for (int c = 0; c < nchunk; ++c) {
#pragma unroll
      for (int dp = 0; dp < 4; ++dp)
        *(unsigned*)&Xs[lane * 36 + w * 8 + dp * 2] = cvtpk(xf0[dp], xf1[dp]);
#pragma unroll
      for (int dp = 0; dp < 8; ++dp)
        *(unsigned*)&Ws[iw * 36 + g * 16 + dp * 2] = cvtpk(wf0[dp], wf1[dp]);
      __syncthreads();
      if (c + 1 < nchunk) { loadX((c + 1) * 32); loadW((c + 1) * 32); }
      if (which != 2) {
        short8 a[4], b[2];
#pragma unroll
        for (int tg = 0; tg < 4; ++tg)
          a[tg] = ldsfrag(&Xs[(tg * 16 + n16) * 36 + quad * 8]);
#pragma unroll
        for (int cg = 0; cg < 2; ++cg)
          b[cg] = ldsfrag(&Ws[(w * 32 + cg * 16 + n16) * 36 + quad * 8]);
#pragma unroll
        for (int tg = 0; tg < 4; ++tg)
#pragma unroll
          for (int cg = 0; cg < 2; ++cg)
            acc[tg * 2 + cg] = __builtin_amdgcn_mfma_f32_16x16x32_bf16(
                a[tg], b[cg], acc[tg * 2 + cg], 0, 0, 0);
      } else {
        short8 a[2], b[4];
#pragma unroll
        for (int ig = 0; ig < 2; ++ig)
          a[ig] = ldsfrag(&Ws[(w * 32 + ig * 16 + n16) * 36 + quad * 8]);
#pragma unroll
        for (int tg = 0; tg < 4; ++tg)
          b[tg] = ldsfrag(&Xs[(tg * 16 + n16) * 36 + quad * 8]);
#pragma unroll
        for (int ig = 0; ig < 2; ++ig)
#pragma unroll
          for (int tg = 0; tg < 4; ++tg)
            acc[ig * 4 + tg] = __builtin_amdgcn_mfma_f32_16x16x32_bf16(
                a[ig], b[tg], acc[ig * 4 + tg], 0, 0, 0);
      }
      __syncthreads();
    }

    if (which != 2) {
      short* Yb = Y + ((size_t)bt * NH + w) * NTOK * HD;
#pragma unroll
      for (int tg = 0; tg < 4; ++tg)
#pragma unroll
        for (int cg = 0; cg < 2; ++cg) {
          f32x4 a = acc[tg * 2 + cg];
#pragma unroll
          for (int r = 0; r < 4; ++r) {
            int tok = n0 + tg * 16 + quad * 4 + r;
            Yb[(size_t)tok * HD + cg * 16 + n16] = f2b(a[r] * scl);
          }
        }
    } else {
#pragma unroll
      for (int ig = 0; ig < 2; ++ig)
#pragma unroll
        for (int tg = 0; tg < 4; ++tg) {
          f32x4 a = acc[ig * 4 + tg];
#pragma unroll
          for (int r = 0; r < 4; ++r) {
            int irow = w * 32 + ig * 16 + quad * 4 + r;
            Y[((size_t)bt * INNER + irow) * NTOK + n0 + tg * 16 + n16] =
                f2b(a[r]);
          }
        }
    }
  }
}

// ---- MFMA attention, 32x32 shape, in-register P transpose -----------------
// grid 1600: id>>5 = 32-q tile (50), id&31 = (bt,h). Wave w covers k-range
// (416/416/384/384). Per 32k chunk: S^T = K x Q (2x mfma_32x32x16),
// exp2 (log2e pre-folded into Q), v_cvt_pk_bf16_f32 pack, permlane32_swap
// cross-half exchange builds the PV B-operand in-register, O^T += V x P^T.
// K and V both register-prefetched one chunk ahead. K-split partials
// combined through an 8.5 KB LDS buffer in two stages.
__global__ __launch_bounds__(256, 5) void attn_mfma(
    const short* __restrict__ Qb, const short* __restrict__ Kb,
    const short* __restrict__ Vb, short* __restrict__ Obf) {
  const int id = blockIdx.x;
  const int qt = id >> 5;
  const int pair = id & 31;
  const int bt = pair >> 2, h = pair & 3;
  const int wave = threadIdx.x >> 6, lane = threadIdx.x & 63;
  const int lh = lane >> 5, q32 = lane & 31;
  const int q0 = qt * 32;
  const size_t btok = ((size_t)bt * NH + h) * NTOK;
  const size_t bd = ((size_t)bt * NH + h) * HD;

  __shared__ float Cb[2][17][64];  // 8.5 KB combine buffers

  const short* Qp = &Qb[(btok + q0 + q32) * HD + lh * 8];
  const short8 bq0 = *(const short8*)(Qp);
  const short8 bq1 = *(const short8*)(Qp + 16);

  const int kstart = wave * 416 - (wave == 3 ? 32 : 0);
  const int nch = 13 - (wave >> 1);
  const short* Kp = &Kb[(btok + kstart + q32) * HD + lh * 8];
  const short* Vp = &Vb[(bd + q32) * NTOK + kstart + lh * 8];

  f32x16 o = {0.f, 0.f, 0.f, 0.f, 0.f, 0.f, 0.f, 0.f,
              0.f, 0.f, 0.f, 0.f, 0.f, 0.f, 0.f, 0.f};
  f32x2 ls2 = {0.f, 0.f};

  short8 ak0 = *(const short8*)(Kp);
  short8 ak1 = *(const short8*)(Kp + 16);
  short8 av0 = *(const short8*)(Vp);
  short8 av1 = *(const short8*)(Vp + 16);

  for (int i = 0; i < nch; ++i) {
    const int kn = (i + 1 < nch) ? (i + 1) * 32 : 0;
    short8 nk0 = *(const short8*)(Kp + (size_t)kn * HD);
    short8 nk1 = *(const short8*)(Kp + (size_t)kn * HD + 16);
    short8 nv0 = *(const short8*)(Vp + kn);
    short8 nv1 = *(const short8*)(Vp + kn + 16);

    __builtin_amdgcn_s_setprio(1);
    f32x16 s = __builtin_amdgcn_mfma_f32_32x32x16_bf16(
        ak0, bq0,
        (f32x16){0.f, 0.f, 0.f, 0.f, 0.f, 0.f, 0.f, 0.f,
                 0.f, 0.f, 0.f, 0.f, 0.f, 0.f, 0.f, 0.f},
        0, 0, 0);
    s = __builtin_amdgcn_mfma_f32_32x32x16_bf16(ak1, bq1, s, 0, 0, 0);
    __builtin_amdgcn_s_setprio(0);

    // exp2 + pack: reg r holds S^T[k][q], k = (r&3) + 8*(r>>2) + 4*lh
    unsigned Pd[8];
#pragma unroll
    for (int g = 0; g < 4; ++g) {
      float e0 = __builtin_amdgcn_exp2f(s[4 * g + 0]);
      float e1 = __builtin_amdgcn_exp2f(s[4 * g + 1]);
      float e2 = __builtin_amdgcn_exp2f(s[4 * g + 2]);
      float e3 = __builtin_amdgcn_exp2f(s[4 * g + 3]);
      ls2 += (f32x2){e0, e1};
      ls2 += (f32x2){e2, e3};
      Pd[2 * g + 0] = cvtpk(e0, e1);
      Pd[2 * g + 1] = cvtpk(e2, e3);
    }
    // cross-half exchange in-register. pswap(a,b): a.row1 <-> b.row0, so
    //  Pd[0]' = {lo: own k0k1,        hi: lo-half's k8k9 }  = B dword0
    //  Pd[2]' = {lo: hi-half's k4k5,  hi: own k12k13     }  = B dword2
    pswap(Pd[0], Pd[2]);
    pswap(Pd[1], Pd[3]);
    pswap(Pd[4], Pd[6]);
    pswap(Pd[5], Pd[7]);
    short8 pb0 = mk8(Pd[0], Pd[1], Pd[2], Pd[3]);
    short8 pb1 = mk8(Pd[4], Pd[5], Pd[6], Pd[7]);

    __builtin_amdgcn_s_setprio(1);
    o = __builtin_amdgcn_mfma_f32_32x32x16_bf16(av0, pb0, o, 0, 0, 0);
    o = __builtin_amdgcn_mfma_f32_32x32x16_bf16(av1, pb1, o, 0, 0, 0);
    __builtin_amdgcn_s_setprio(0);

    ak0 = nk0; ak1 = nk1; av0 = nv0; av1 = nv1;
  }

  float lsum = ls2[0] + ls2[1];
  lsum += __shfl_xor(lsum, 32);  // full row sum over both halves

  // two-stage combine across waves (8.5 KB LDS)
  auto dump = [&](int sidx) {
#pragma unroll
    for (int r = 0; r < 16; ++r) Cb[sidx][r][lane] = o[r];
    Cb[sidx][16][lane] = lsum;
  };
  auto accum = [&](int sidx) {
#pragma unroll
    for (int r = 0; r < 16; ++r) o[r] += Cb[sidx][r][lane];
    lsum += Cb[sidx][16][lane];
  };
  if (wave == 1) dump(0);
  if (wave == 3) dump(1);
  __syncthreads();
  if (wave == 0) accum(0);
  if (wave == 2) accum(1);
  __syncthreads();
  if (wave == 2) dump(0);
  __syncthreads();
  if (wave == 0) {
    accum(0);
    const float inv = 1.f / lsum;
    // O^T C-layout: col q = q32, row d = (r&3)+8*(r>>2)+4*lh
    short* Op = &Obf[((size_t)bt * NTOK + q0 + q32) * INNER + h * HD + lh * 4];
#pragma unroll
    for (int g = 0; g < 4; ++g) {
      unsigned d0 = cvtpk(o[4 * g + 0] * inv, o[4 * g + 1] * inv);
      unsigned d1 = cvtpk(o[4 * g + 2] * inv, o[4 * g + 3] * inv);
      *(uint2*)&Op[8 * g] = make_uint2(d0, d1);
    }
  }
}

// ---- output projection (MFMA). grid (25, 4, 8): 64 tok x 64 dout tiles ----
__global__ __launch_bounds__(256) void oproj_mfma(
    const short* __restrict__ Obf, const float* __restrict__ Wo,
    const float* __restrict__ bo, float* __restrict__ out) {
  const int tok0 = blockIdx.x * 64, d0 = blockIdx.y * 64;
  const int bt = blockIdx.z;
  const int t = threadIdx.x, lane = t & 63, w = t >> 6;
  const int quad = lane >> 4, n16 = lane & 15;
  __shared__ short Wos[64 * 36];  // [dout][i] bf16
  f32x4 acc[4];
#pragma unroll
  for (int i = 0; i < 4; ++i) acc[i] = (f32x4){0.f, 0.f, 0.f, 0.f};
  const int tok = tok0 + w * 16 + n16;  // always < 1600

  float wf0[4], wf1[4];
  short8 bfr;
  auto loadWo = [&](int c) {
#pragma unroll
    for (int dp = 0; dp < 4; ++dp) {
      int il = w * 8 + dp * 2;
      wf0[dp] = Wo[(size_t)(c * 32 + il) * QDIM + d0 + lane];
      wf1[dp] = Wo[(size_t)(c * 32 + il + 1) * QDIM + d0 + lane];
    }
  };
  auto loadB = [&](int c) {
    bfr = *(const short8*)&Obf[((size_t)bt * NTOK + tok) * INNER + c * 32 +
                               quad * 8];
  };
  loadWo(0); loadB(0);

  for (int c = 0; c < 4; ++c) {
#pragma unroll
    for (int dp = 0; dp < 4; ++dp)
      *(unsigned*)&Wos[lane * 36 + w * 8 + dp * 2] = cvtpk(wf0[dp], wf1[dp]);
    __syncthreads();
    short8 b0 = bfr;
    if (c < 3) { loadWo(c + 1); loadB(c + 1); }
#pragma unroll
    for (int ag = 0; ag < 4; ++ag) {
      short8 a = ldsfrag(&Wos[(ag * 16 + n16) * 36 + quad * 8]);
      acc[ag] = __builtin_amdgcn_mfma_f32_16x16x32_bf16(a, b0, acc[ag], 0, 0, 0);
    }
    __syncthreads();
  }

#pragma unroll
  for (int ag = 0; ag < 4; ++ag) {
    f32x4 a = acc[ag];
#pragma unroll
    for (int r = 0; r < 4; ++r) {
      int dout = d0 + ag * 16 + quad * 4 + r;
      out[((size_t)bt * QDIM + dout) * NTOK + tok] = a[r] + bo[dout];
    }
  }
}

extern "C" void kernel_launch(void* const* d_in, const int* in_sizes, int n_in,
                              void* d_out, int out_size, void* d_ws,
                              size_t ws_size, hipStream_t stream) {
  const float* query = (const float*)d_in[0];
  const float* key = (const float*)d_in[1];
  const float* value = (const float*)d_in[2];
  const float* Wq = (const float*)d_in[3];
  const float* Wk = (const float*)d_in[4];
  const float* Wv = (const float*)d_in[5];
  const float* Wo = (const float*)d_in[6];
  const float* bo = (const float*)d_in[7];
  float* out = (float*)d_out;

  const size_t arr = (size_t)BT_TOTAL * INNER * NTOK;
  short* Qbf = (short*)d_ws;
  short* Kbf = Qbf + arr;
  short* Vbf = Kbf + arr;
  short* Obf = Vbf + arr;

  proj_fused<<<dim3(25, 3, BT_TOTAL), 256, 0, stream>>>(
      query, Wq, key, Wk, value, Wv, Qbf, Kbf, Vbf);
  attn_mfma<<<dim3(1600), 256, 0, stream>>>(Qbf, Kbf, Vbf, Obf);
  oproj_mfma<<<dim3(25, 4, BT_TOTAL), 256, 0, stream>>>(Obf, Wo, bo, out);
}

// Round 5
// 134.817 us; speedup vs baseline: 2.8613x; 1.5482x over previous
//
#include <hip/hip_runtime.h>

#define NTOK 1600
#define BT_TOTAL 8
#define INNER 128
#define HD 32
#define NH 4
#define QDIM 256

typedef short short8 __attribute__((ext_vector_type(8)));
typedef short short4v __attribute__((ext_vector_type(4)));
typedef float f32x2 __attribute__((ext_vector_type(2)));
typedef float f32x4 __attribute__((ext_vector_type(4)));
typedef float f32x16 __attribute__((ext_vector_type(16)));
typedef unsigned uint2v __attribute__((ext_vector_type(2)));

__device__ inline short f2b(float x) {  // fp32 -> bf16, RNE-ish (scattered stores)
  union { float f; unsigned u; } v; v.f = x;
  unsigned r = (v.u + 0x7FFF + ((v.u >> 16) & 1)) >> 16;
  return (short)r;
}
// packed bf16 convert: lo16 = bf16(a), hi16 = bf16(b), RNE, single VALU op
__device__ inline unsigned cvtpk(float a, float b) {
  unsigned r;
  asm("v_cvt_pk_bf16_f32 %0, %1, %2" : "=v"(r) : "v"(a), "v"(b));
  return r;
}
// v_permlane32_swap_b32: block-transpose primitive.
// Exchanges a.row1 (lanes 32-63) with b.row0 (lanes 0-31):
//   a' = {lanes 0-31: a[0:31],  lanes 32-63: b[0:31]}
//   b' = {lanes 0-31: a[32:63], lanes 32-63: b[32:63]}
__device__ inline void pswap(unsigned &a, unsigned &b) {
  uint2v r = __builtin_amdgcn_permlane32_swap(a, b, false, false);
  a = r[0]; b = r[1];
}
// LDS fragment load from 8B-aligned rows (stride 36 shorts): two b64 reads
__device__ inline short8 ldsfrag(const short* p) {
  short4v a = *(const short4v*)p;
  short4v b = *(const short4v*)(p + 4);
  short8 r;
  r[0] = a[0]; r[1] = a[1]; r[2] = a[2]; r[3] = a[3];
  r[4] = b[0]; r[5] = b[1]; r[6] = b[2]; r[7] = b[3];
  return r;
}
__device__ inline short8 mk8(unsigned a, unsigned b, unsigned c, unsigned d) {
  union { unsigned u[4]; short8 v; } t;
  t.u[0] = a; t.u[1] = b; t.u[2] = c; t.u[3] = d;
  return t.v;
}

// ---- fused QKV projection (MFMA), register-prefetched staging -------------
// which=0: Q (scaled by 1/sqrt(32)*log2(e), so attn uses exp2 directly)
//          token-major [bt][h][tok][32]
// which=1: K token-major [bt][h][tok][32]
// which=2: V d-major [bt][i][tok]
__global__ __launch_bounds__(256) void proj_fused(
    const float* __restrict__ query, const float* __restrict__ Wq,
    const float* __restrict__ key, const float* __restrict__ Wk,
    const float* __restrict__ value, const float* __restrict__ Wv,
    short* __restrict__ Qbf, short* __restrict__ Kbf,
    short* __restrict__ Vbf) {
  const int n0 = blockIdx.x * 64;
  const int which = blockIdx.y;
  const int bt = blockIdx.z;
  const int t = threadIdx.x;
  const int lane = t & 63, w = t >> 6;
  const int quad = lane >> 4, n16 = lane & 15;

  const float* X; const float* Wt; short* Y; int nchunk; float scl;
  if (which == 0) {
    X = query; Wt = Wq; Y = Qbf; nchunk = 8;
    scl = 0.17677669529663687f * 1.4426950408889634f;  // fold log2(e)
  } else if (which == 1) {
    X = key; Wt = Wk; Y = Kbf; nchunk = 4; scl = 1.0f;
  } else {
    X = value; Wt = Wv; Y = Vbf; nchunk = 4; scl = 1.0f;
  }
  const float* Xb = X + (size_t)bt * (nchunk * 32) * NTOK;

  __shared__ short Xs[64 * 36];   // [tok][d] bf16
  __shared__ short Ws[128 * 36];  // [i][d] bf16

  f32x4 acc[8];
#pragma unroll
  for (int i = 0; i < 8; ++i) acc[i] = (f32x4){0.f, 0.f, 0.f, 0.f};

  const int iw = t & 127, g = t >> 7;

  float xf0[4], xf1[4], wf0[8], wf1[8];
  auto loadX = [&](int cd) {
#pragma unroll
    for (int dp = 0; dp < 4; ++dp) {
      int dl = w * 8 + dp * 2;
      xf0[dp] = Xb[(size_t)(cd + dl) * NTOK + n0 + lane];
      xf1[dp] = Xb[(size_t)(cd + dl + 1) * NTOK + n0 + lane];
    }
  };
  auto loadW = [&](int cd) {
#pragma unroll
    for (int dp = 0; dp < 8; ++dp) {
      int dl = g * 16 + dp * 2;
      wf0[dp] = Wt[(size_t)(cd + dl) * INNER + iw];
      wf1[dp] = Wt[(size_t)(cd + dl + 1) * INNER + iw];
    }
  };
  loadX(0); loadW(0);

  for (int c = 0; c < nchunk; ++c) {
#pragma unroll
    for (int dp = 0; dp < 4; ++dp)
      *(unsigned*)&Xs[lane * 36 + w * 8 + dp * 2] = cvtpk(xf0[dp], xf1[dp]);
#pragma unroll
    for (int dp = 0; dp < 8; ++dp)
      *(unsigned*)&Ws[iw * 36 + g * 16 + dp * 2] = cvtpk(wf0[dp], wf1[dp]);
    __syncthreads();
    if (c + 1 < nchunk) { loadX((c + 1) * 32); loadW((c + 1) * 32); }
    if (which != 2) {
      short8 a[4], b[2];
#pragma unroll
      for (int tg = 0; tg < 4; ++tg)
        a[tg] = ldsfrag(&Xs[(tg * 16 + n16) * 36 + quad * 8]);
#pragma unroll
      for (int cg = 0; cg < 2; ++cg)
        b[cg] = ldsfrag(&Ws[(w * 32 + cg * 16 + n16) * 36 + quad * 8]);
#pragma unroll
      for (int tg = 0; tg < 4; ++tg)
#pragma unroll
        for (int cg = 0; cg < 2; ++cg)
          acc[tg * 2 + cg] = __builtin_amdgcn_mfma_f32_16x16x32_bf16(
              a[tg], b[cg], acc[tg * 2 + cg], 0, 0, 0);
    } else {
      short8 a[2], b[4];
#pragma unroll
      for (int ig = 0; ig < 2; ++ig)
        a[ig] = ldsfrag(&Ws[(w * 32 + ig * 16 + n16) * 36 + quad * 8]);
#pragma unroll
      for (int tg = 0; tg < 4; ++tg)
        b[tg] = ldsfrag(&Xs[(tg * 16 + n16) * 36 + quad * 8]);
#pragma unroll
      for (int ig = 0; ig < 2; ++ig)
#pragma unroll
        for (int tg = 0; tg < 4; ++tg)
          acc[ig * 4 + tg] = __builtin_amdgcn_mfma_f32_16x16x32_bf16(
              a[ig], b[tg], acc[ig * 4 + tg], 0, 0, 0);
    }
    __syncthreads();
  }

  if (which != 2) {
    short* Yb = Y + ((size_t)bt * NH + w) * NTOK * HD;
#pragma unroll
    for (int tg = 0; tg < 4; ++tg)
#pragma unroll
      for (int cg = 0; cg < 2; ++cg) {
        f32x4 a = acc[tg * 2 + cg];
#pragma unroll
        for (int r = 0; r < 4; ++r) {
          int tok = n0 + tg * 16 + quad * 4 + r;
          Yb[(size_t)tok * HD + cg * 16 + n16] = f2b(a[r] * scl);
        }
      }
  } else {
#pragma unroll
    for (int ig = 0; ig < 2; ++ig)
#pragma unroll
      for (int tg = 0; tg < 4; ++tg) {
        f32x4 a = acc[ig * 4 + tg];
#pragma unroll
        for (int r = 0; r < 4; ++r) {
          int irow = w * 32 + ig * 16 + quad * 4 + r;
          Y[((size_t)bt * INNER + irow) * NTOK + n0 + tg * 16 + n16] =
              f2b(a[r]);
        }
      }
  }
}

// ---- MFMA attention, 32x32 shape, 2-chunk ping-pong software pipeline -----
// grid 1600: id>>5 = 32-q tile (50), id&31 = (bt,h). Wave w covers k-range
// (416/416/384/384). Steady state per chunk step:
//   issue K/V loads for chunk c+2  (1.5 steps of latency cover)
//   softmax(s_c) on VALU/trans     (s_c was MFMA'd one step earlier)
//   s_{c+1} = K_{c+1} x Q          (MFMA pipe, result needed next step)
//   O += V_c x P_c^T               (MFMA pipe, pb just produced)
// Breaks the old serial S->exp->pack->PV chain; no setprio (it pinned order).
// K-split partials combined through an 8.5 KB LDS buffer in two stages.
__global__ __launch_bounds__(256, 4) void attn_mfma(
    const short* __restrict__ Qb, const short* __restrict__ Kb,
    const short* __restrict__ Vb, short* __restrict__ Obf) {
  const int id = blockIdx.x;
  const int qt = id >> 5;
  const int pair = id & 31;
  const int bt = pair >> 2, h = pair & 3;
  const int wave = threadIdx.x >> 6, lane = threadIdx.x & 63;
  const int lh = lane >> 5, q32 = lane & 31;
  const int q0 = qt * 32;
  const size_t btok = ((size_t)bt * NH + h) * NTOK;
  const size_t bd = ((size_t)bt * NH + h) * HD;

  __shared__ float Cb[2][17][64];  // 8.5 KB combine buffers

  const short* Qp = &Qb[(btok + q0 + q32) * HD + lh * 8];
  const short8 bq0 = *(const short8*)(Qp);
  const short8 bq1 = *(const short8*)(Qp + 16);

  const int kstart = wave * 416 - (wave == 3 ? 32 : 0);
  const int nch = 13 - (wave >> 1);
  const short* Kp = &Kb[(btok + kstart + q32) * HD + lh * 8];
  const short* Vp = &Vb[(bd + q32) * NTOK + kstart + lh * 8];

  f32x16 o = {0.f, 0.f, 0.f, 0.f, 0.f, 0.f, 0.f, 0.f,
              0.f, 0.f, 0.f, 0.f, 0.f, 0.f, 0.f, 0.f};
  f32x2 ls2 = {0.f, 0.f};

  // exp2 + pack + cross-half exchange: S^T[k][q] regs -> PV B-operand frags.
  // reg r of sv holds S^T[k][q32], k = (r&3) + 8*(r>>2) + 4*lh.
  auto softmax_pack = [&](const f32x16& sv, short8& pb0, short8& pb1) {
    unsigned Pd[8];
#pragma unroll
    for (int g = 0; g < 4; ++g) {
      float e0 = __builtin_amdgcn_exp2f(sv[4 * g + 0]);
      float e1 = __builtin_amdgcn_exp2f(sv[4 * g + 1]);
      float e2 = __builtin_amdgcn_exp2f(sv[4 * g + 2]);
      float e3 = __builtin_amdgcn_exp2f(sv[4 * g + 3]);
      ls2 += (f32x2){e0, e1};
      ls2 += (f32x2){e2, e3};
      Pd[2 * g + 0] = cvtpk(e0, e1);
      Pd[2 * g + 1] = cvtpk(e2, e3);
    }
    // pswap(a,b): a.row1 <-> b.row0 =>
    //  Pd[0]' = {lo: own k0k1,        hi: lo-half's k8k9 }  = B dword0
    //  Pd[2]' = {lo: hi-half's k4k5,  hi: own k12k13     }  = B dword2
    pswap(Pd[0], Pd[2]);
    pswap(Pd[1], Pd[3]);
    pswap(Pd[4], Pd[6]);
    pswap(Pd[5], Pd[7]);
    pb0 = mk8(Pd[0], Pd[1], Pd[2], Pd[3]);
    pb1 = mk8(Pd[4], Pd[5], Pd[6], Pd[7]);
  };

  const f32x16 zero16 = {0.f, 0.f, 0.f, 0.f, 0.f, 0.f, 0.f, 0.f,
                         0.f, 0.f, 0.f, 0.f, 0.f, 0.f, 0.f, 0.f};
  // chunk c element offset helpers (wrap OOB prefetches to chunk 0 -- the
  // loaded garbage is only consumed by discarded score computations)
  auto kidx = [&](int c) -> size_t { return (c < nch) ? (size_t)c * 32 : 0; };

  // prologue: chunks 0,1 in flight; scores(0)
  short8 kA0 = *(const short8*)(Kp);
  short8 kA1 = *(const short8*)(Kp + 16);
  short8 vA0 = *(const short8*)(Vp);
  short8 vA1 = *(const short8*)(Vp + 16);
  short8 kB0 = *(const short8*)(Kp + (size_t)32 * HD);
  short8 kB1 = *(const short8*)(Kp + (size_t)32 * HD + 16);
  short8 vB0 = *(const short8*)(Vp + 32);
  short8 vB1 = *(const short8*)(Vp + 32 + 16);

  f32x16 s = __builtin_amdgcn_mfma_f32_32x32x16_bf16(kA0, bq0, zero16, 0, 0, 0);
  s = __builtin_amdgcn_mfma_f32_32x32x16_bf16(kA1, bq1, s, 0, 0, 0);
  f32x16 s2;
  short8 pb0, pb1;

  const int npair = nch >> 1;  // 6 for nch=13 and nch=12
#pragma unroll 1
  for (int tp = 0; tp < npair; ++tp) {
    const int c = 2 * tp;
    {  // even step: finish chunk c
      const size_t kn = kidx(c + 2);
      kA0 = *(const short8*)(Kp + kn * HD);          // issue K(c+2)
      kA1 = *(const short8*)(Kp + kn * HD + 16);
      softmax_pack(s, pb0, pb1);                     // VALU: chunk c
      s2 = __builtin_amdgcn_mfma_f32_32x32x16_bf16(kB0, bq0, zero16, 0, 0, 0);
      s2 = __builtin_amdgcn_mfma_f32_32x32x16_bf16(kB1, bq1, s2, 0, 0, 0);
      o = __builtin_amdgcn_mfma_f32_32x32x16_bf16(vA0, pb0, o, 0, 0, 0);
      o = __builtin_amdgcn_mfma_f32_32x32x16_bf16(vA1, pb1, o, 0, 0, 0);
      vA0 = *(const short8*)(Vp + kn);               // issue V(c+2)
      vA1 = *(const short8*)(Vp + kn + 16);
    }
    {  // odd step: finish chunk c+1
      const size_t kn = kidx(c + 3);
      kB0 = *(const short8*)(Kp + kn * HD);          // issue K(c+3)
      kB1 = *(const short8*)(Kp + kn * HD + 16);
      softmax_pack(s2, pb0, pb1);                    // VALU: chunk c+1
      s = __builtin_amdgcn_mfma_f32_32x32x16_bf16(kA0, bq0, zero16, 0, 0, 0);
      s = __builtin_amdgcn_mfma_f32_32x32x16_bf16(kA1, bq1, s, 0, 0, 0);
      o = __builtin_amdgcn_mfma_f32_32x32x16_bf16(vB0, pb0, o, 0, 0, 0);
      o = __builtin_amdgcn_mfma_f32_32x32x16_bf16(vB1, pb1, o, 0, 0, 0);
      vB0 = *(const short8*)(Vp + kn);               // issue V(c+3)
      vB1 = *(const short8*)(Vp + kn + 16);
    }
  }
  if (nch & 1) {  // tail chunk nch-1 (even index -> vA, s holds its scores)
    softmax_pack(s, pb0, pb1);
    o = __builtin_amdgcn_mfma_f32_32x32x16_bf16(vA0, pb0, o, 0, 0, 0);
    o = __builtin_amdgcn_mfma_f32_32x32x16_bf16(vA1, pb1, o, 0, 0, 0);
  }

  float lsum = ls2[0] + ls2[1];
  lsum += __shfl_xor(lsum, 32);  // full row sum over both halves

  // two-stage combine across waves (8.5 KB LDS)
  auto dump = [&](int sidx) {
#pragma unroll
    for (int r = 0; r < 16; ++r) Cb[sidx][r][lane] = o[r];
    Cb[sidx][16][lane] = lsum;
  };
  auto accum = [&](int sidx) {
#pragma unroll
    for (int r = 0; r < 16; ++r) o[r] += Cb[sidx][r][lane];
    lsum += Cb[sidx][16][lane];
  };
  if (wave == 1) dump(0);
  if (wave == 3) dump(1);
  __syncthreads();
  if (wave == 0) accum(0);
  if (wave == 2) accum(1);
  __syncthreads();
  if (wave == 2) dump(0);
  __syncthreads();
  if (wave == 0) {
    accum(0);
    const float inv = 1.f / lsum;
    // O^T C-layout: col q = q32, row d = (r&3)+8*(r>>2)+4*lh
    short* Op = &Obf[((size_t)bt * NTOK + q0 + q32) * INNER + h * HD + lh * 4];
#pragma unroll
    for (int g = 0; g < 4; ++g) {
      unsigned d0 = cvtpk(o[4 * g + 0] * inv, o[4 * g + 1] * inv);
      unsigned d1 = cvtpk(o[4 * g + 2] * inv, o[4 * g + 3] * inv);
      *(uint2*)&Op[8 * g] = make_uint2(d0, d1);
    }
  }
}

// ---- output projection (MFMA). grid (25, 4, 8): 64 tok x 64 dout tiles ----
__global__ __launch_bounds__(256) void oproj_mfma(
    const short* __restrict__ Obf, const float* __restrict__ Wo,
    const float* __restrict__ bo, float* __restrict__ out) {
  const int tok0 = blockIdx.x * 64, d0 = blockIdx.y * 64;
  const int bt = blockIdx.z;
  const int t = threadIdx.x, lane = t & 63, w = t >> 6;
  const int quad = lane >> 4, n16 = lane & 15;
  __shared__ short Wos[64 * 36];  // [dout][i] bf16
  f32x4 acc[4];
#pragma unroll
  for (int i = 0; i < 4; ++i) acc[i] = (f32x4){0.f, 0.f, 0.f, 0.f};
  const int tok = tok0 + w * 16 + n16;  // always < 1600

  float wf0[4], wf1[4];
  short8 bfr;
  auto loadWo = [&](int c) {
#pragma unroll
    for (int dp = 0; dp < 4; ++dp) {
      int il = w * 8 + dp * 2;
      wf0[dp] = Wo[(size_t)(c * 32 + il) * QDIM + d0 + lane];
      wf1[dp] = Wo[(size_t)(c * 32 + il + 1) * QDIM + d0 + lane];
    }
  };
  auto loadB = [&](int c) {
    bfr = *(const short8*)&Obf[((size_t)bt * NTOK + tok) * INNER + c * 32 +
                               quad * 8];
  };
  loadWo(0); loadB(0);

  for (int c = 0; c < 4; ++c) {
#pragma unroll
    for (int dp = 0; dp < 4; ++dp)
      *(unsigned*)&Wos[lane * 36 + w * 8 + dp * 2] = cvtpk(wf0[dp], wf1[dp]);
    __syncthreads();
    short8 b0 = bfr;
    if (c < 3) { loadWo(c + 1); loadB(c + 1); }
#pragma unroll
    for (int ag = 0; ag < 4; ++ag) {
      short8 a = ldsfrag(&Wos[(ag * 16 + n16) * 36 + quad * 8]);
      acc[ag] = __builtin_amdgcn_mfma_f32_16x16x32_bf16(a, b0, acc[ag], 0, 0, 0);
    }
    __syncthreads();
  }

#pragma unroll
  for (int ag = 0; ag < 4; ++ag) {
    f32x4 a = acc[ag];
#pragma unroll
    for (int r = 0; r < 4; ++r) {
      int dout = d0 + ag * 16 + quad * 4 + r;
      out[((size_t)bt * QDIM + dout) * NTOK + tok] = a[r] + bo[dout];
    }
  }
}

extern "C" void kernel_launch(void* const* d_in, const int* in_sizes, int n_in,
                              void* d_out, int out_size, void* d_ws,
                              size_t ws_size, hipStream_t stream) {
  const float* query = (const float*)d_in[0];
  const float* key = (const float*)d_in[1];
  const float* value = (const float*)d_in[2];
  const float* Wq = (const float*)d_in[3];
  const float* Wk = (const float*)d_in[4];
  const float* Wv = (const float*)d_in[5];
  const float* Wo = (const float*)d_in[6];
  const float* bo = (const float*)d_in[7];
  float* out = (float*)d_out;

  const size_t arr = (size_t)BT_TOTAL * INNER * NTOK;
  short* Qbf = (short*)d_ws;
  short* Kbf = Qbf + arr;
  short* Vbf = Kbf + arr;
  short* Obf = Vbf + arr;

  proj_fused<<<dim3(25, 3, BT_TOTAL), 256, 0, stream>>>(
      query, Wq, key, Wk, value, Wv, Qbf, Kbf, Vbf);
  attn_mfma<<<dim3(1600), 256, 0, stream>>>(Qbf, Kbf, Vbf, Obf);
  oproj_mfma<<<dim3(25, 4, BT_TOTAL), 256, 0, stream>>>(Obf, Wo, bo, out);
}

// Round 6
// 120.607 us; speedup vs baseline: 3.1984x; 1.1178x over previous
//
#include <hip/hip_runtime.h>

#define NTOK 1600
#define BT_TOTAL 8
#define INNER 128
#define HD 32
#define NH 4
#define QDIM 256

typedef short short8 __attribute__((ext_vector_type(8)));
typedef short short4v __attribute__((ext_vector_type(4)));
typedef float f32x2 __attribute__((ext_vector_type(2)));
typedef float f32x4 __attribute__((ext_vector_type(4)));
typedef float f32x16 __attribute__((ext_vector_type(16)));
typedef unsigned uint2v __attribute__((ext_vector_type(2)));

__device__ inline short f2b(float x) {  // fp32 -> bf16, RNE-ish (scattered stores)
  union { float f; unsigned u; } v; v.f = x;
  unsigned r = (v.u + 0x7FFF + ((v.u >> 16) & 1)) >> 16;
  return (short)r;
}
// packed bf16 convert: lo16 = bf16(a), hi16 = bf16(b), RNE, single VALU op
__device__ inline unsigned cvtpk(float a, float b) {
  unsigned r;
  asm("v_cvt_pk_bf16_f32 %0, %1, %2" : "=v"(r) : "v"(a), "v"(b));
  return r;
}
// v_permlane32_swap_b32: block-transpose primitive.
// Exchanges a.row1 (lanes 32-63) with b.row0 (lanes 0-31):
//   a' = {lanes 0-31: a[0:31],  lanes 32-63: b[0:31]}
//   b' = {lanes 0-31: a[32:63], lanes 32-63: b[32:63]}
__device__ inline void pswap(unsigned &a, unsigned &b) {
  uint2v r = __builtin_amdgcn_permlane32_swap(a, b, false, false);
  a = r[0]; b = r[1];
}
// LDS fragment load from 8B-aligned rows (stride 36 shorts): two b64 reads
__device__ inline short8 ldsfrag(const short* p) {
  short4v a = *(const short4v*)p;
  short4v b = *(const short4v*)(p + 4);
  short8 r;
  r[0] = a[0]; r[1] = a[1]; r[2] = a[2]; r[3] = a[3];
  r[4] = b[0]; r[5] = b[1]; r[6] = b[2]; r[7] = b[3];
  return r;
}
__device__ inline short8 mk8(unsigned a, unsigned b, unsigned c, unsigned d) {
  union { unsigned u[4]; short8 v; } t;
  t.u[0] = a; t.u[1] = b; t.u[2] = c; t.u[3] = d;
  return t.v;
}

// ---- fused QKV projection (MFMA), register-prefetched staging -------------
// which=0: Q (scaled by 1/sqrt(32)*log2(e), so attn uses exp2 directly)
//          token-major [bt][h][tok][32]
// which=1: K token-major [bt][h][tok][32]
// which=2: V d-major [bt][i][tok]
__global__ __launch_bounds__(256) void proj_fused(
    const float* __restrict__ query, const float* __restrict__ Wq,
    const float* __restrict__ key, const float* __restrict__ Wk,
    const float* __restrict__ value, const float* __restrict__ Wv,
    short* __restrict__ Qbf, short* __restrict__ Kbf,
    short* __restrict__ Vbf) {
  const int n0 = blockIdx.x * 64;
  const int which = blockIdx.y;
  const int bt = blockIdx.z;
  const int t = threadIdx.x;
  const int lane = t & 63, w = t >> 6;
  const int quad = lane >> 4, n16 = lane & 15;

  const float* X; const float* Wt; short* Y; int nchunk; float scl;
  if (which == 0) {
    X = query; Wt = Wq; Y = Qbf; nchunk = 8;
    scl = 0.17677669529663687f * 1.4426950408889634f;  // fold log2(e)
  } else if (which == 1) {
    X = key; Wt = Wk; Y = Kbf; nchunk = 4; scl = 1.0f;
  } else {
    X = value; Wt = Wv; Y = Vbf; nchunk = 4; scl = 1.0f;
  }
  const float* Xb = X + (size_t)bt * (nchunk * 32) * NTOK;

  __shared__ short Xs[64 * 36];   // [tok][d] bf16
  __shared__ short Ws[128 * 36];  // [i][d] bf16

  f32x4 acc[8];
#pragma unroll
  for (int i = 0; i < 8; ++i) acc[i] = (f32x4){0.f, 0.f, 0.f, 0.f};

  const int iw = t & 127, g = t >> 7;

  float xf0[4], xf1[4], wf0[8], wf1[8];
  auto loadX = [&](int cd) {
#pragma unroll
    for (int dp = 0; dp < 4; ++dp) {
      int dl = w * 8 + dp * 2;
      xf0[dp] = Xb[(size_t)(cd + dl) * NTOK + n0 + lane];
      xf1[dp] = Xb[(size_t)(cd + dl + 1) * NTOK + n0 + lane];
    }
  };
  auto loadW = [&](int cd) {
#pragma unroll
    for (int dp = 0; dp < 8; ++dp) {
      int dl = g * 16 + dp * 2;
      wf0[dp] = Wt[(size_t)(cd + dl) * INNER + iw];
      wf1[dp] = Wt[(size_t)(cd + dl + 1) * INNER + iw];
    }
  };
  loadX(0); loadW(0);

  for (int c = 0; c < nchunk; ++c) {
#pragma unroll
    for (int dp = 0; dp < 4; ++dp)
      *(unsigned*)&Xs[lane * 36 + w * 8 + dp * 2] = cvtpk(xf0[dp], xf1[dp]);
#pragma unroll
    for (int dp = 0; dp < 8; ++dp)
      *(unsigned*)&Ws[iw * 36 + g * 16 + dp * 2] = cvtpk(wf0[dp], wf1[dp]);
    __syncthreads();
    if (c + 1 < nchunk) { loadX((c + 1) * 32); loadW((c + 1) * 32); }
    if (which != 2) {
      short8 a[4], b[2];
#pragma unroll
      for (int tg = 0; tg < 4; ++tg)
        a[tg] = ldsfrag(&Xs[(tg * 16 + n16) * 36 + quad * 8]);
#pragma unroll
      for (int cg = 0; cg < 2; ++cg)
        b[cg] = ldsfrag(&Ws[(w * 32 + cg * 16 + n16) * 36 + quad * 8]);
#pragma unroll
      for (int tg = 0; tg < 4; ++tg)
#pragma unroll
        for (int cg = 0; cg < 2; ++cg)
          acc[tg * 2 + cg] = __builtin_amdgcn_mfma_f32_16x16x32_bf16(
              a[tg], b[cg], acc[tg * 2 + cg], 0, 0, 0);
    } else {
      short8 a[2], b[4];
#pragma unroll
      for (int ig = 0; ig < 2; ++ig)
        a[ig] = ldsfrag(&Ws[(w * 32 + ig * 16 + n16) * 36 + quad * 8]);
#pragma unroll
      for (int tg = 0; tg < 4; ++tg)
        b[tg] = ldsfrag(&Xs[(tg * 16 + n16) * 36 + quad * 8]);
#pragma unroll
      for (int ig = 0; ig < 2; ++ig)
#pragma unroll
        for (int tg = 0; tg < 4; ++tg)
          acc[ig * 4 + tg] = __builtin_amdgcn_mfma_f32_16x16x32_bf16(
              a[ig], b[tg], acc[ig * 4 + tg], 0, 0, 0);
    }
    __syncthreads();
  }

  if (which != 2) {
    short* Yb = Y + ((size_t)bt * NH + w) * NTOK * HD;
#pragma unroll
    for (int tg = 0; tg < 4; ++tg)
#pragma unroll
      for (int cg = 0; cg < 2; ++cg) {
        f32x4 a = acc[tg * 2 + cg];
#pragma unroll
        for (int r = 0; r < 4; ++r) {
          int tok = n0 + tg * 16 + quad * 4 + r;
          Yb[(size_t)tok * HD + cg * 16 + n16] = f2b(a[r] * scl);
        }
      }
  } else {
#pragma unroll
    for (int ig = 0; ig < 2; ++ig)
#pragma unroll
      for (int tg = 0; tg < 4; ++tg) {
        f32x4 a = acc[ig * 4 + tg];
#pragma unroll
        for (int r = 0; r < 4; ++r) {
          int irow = w * 32 + ig * 16 + quad * 4 + r;
          Y[((size_t)bt * INNER + irow) * NTOK + n0 + tg * 16 + n16] =
              f2b(a[r]);
        }
      }
  }
}

// ---- MFMA attention, 32x32 shape, TWO q-tiles per block -------------------
// grid 800: id>>5 = 64-q tile (25), id&31 = (bt,h). Wave w covers k-range
// (416/416/384/384). Two 32-q tiles (A,B) share one K/V load stream:
// per 32k chunk the 4 L2 loads are amortized over 2x the issue work
// (8 MFMA + 32 exp2 + packs ~ 310 cyc > ~225 cyc L2 latency), so the
// structural per-chunk stall of the 1-tile version is covered at
// prefetch depth 1. Also halves total K/V L2 traffic (800 vs 1600 blocks).
// K-split partials combined through a 17 KB LDS buffer in two stages.
__global__ __launch_bounds__(256, 3) void attn_mfma(
    const short* __restrict__ Qb, const short* __restrict__ Kb,
    const short* __restrict__ Vb, short* __restrict__ Obf) {
  const int id = blockIdx.x;
  const int qt = id >> 5;
  const int pair = id & 31;
  const int bt = pair >> 2, h = pair & 3;
  const int wave = threadIdx.x >> 6, lane = threadIdx.x & 63;
  const int lh = lane >> 5, q32 = lane & 31;
  const int q0 = qt * 64;
  const size_t btok = ((size_t)bt * NH + h) * NTOK;
  const size_t bd = ((size_t)bt * NH + h) * HD;

  __shared__ float Cb[2][2][17][64];  // [tile][stage][row][lane], 17.4 KB

  const short* QpA = &Qb[(btok + q0 + q32) * HD + lh * 8];
  const short* QpB = QpA + 32 * HD;
  const short8 bqA0 = *(const short8*)(QpA);
  const short8 bqA1 = *(const short8*)(QpA + 16);
  const short8 bqB0 = *(const short8*)(QpB);
  const short8 bqB1 = *(const short8*)(QpB + 16);

  const int kstart = wave * 416 - (wave == 3 ? 32 : 0);
  const int nch = 13 - (wave >> 1);
  const short* Kp = &Kb[(btok + kstart + q32) * HD + lh * 8];
  const short* Vp = &Vb[(bd + q32) * NTOK + kstart + lh * 8];

  const f32x16 zero16 = {0.f, 0.f, 0.f, 0.f, 0.f, 0.f, 0.f, 0.f,
                         0.f, 0.f, 0.f, 0.f, 0.f, 0.f, 0.f, 0.f};
  f32x16 oA = zero16, oB = zero16;
  f32x2 lsA = {0.f, 0.f}, lsB = {0.f, 0.f};

  // exp2 + pack + cross-half exchange: S^T[k][q] regs -> PV B-operand frags.
  // reg r of sv holds S^T[k][q32], k = (r&3) + 8*(r>>2) + 4*lh.
  auto softmax_pack = [&](const f32x16& sv, f32x2& ls2, short8& pb0,
                          short8& pb1) {
    unsigned Pd[8];
#pragma unroll
    for (int g = 0; g < 4; ++g) {
      float e0 = __builtin_amdgcn_exp2f(sv[4 * g + 0]);
      float e1 = __builtin_amdgcn_exp2f(sv[4 * g + 1]);
      float e2 = __builtin_amdgcn_exp2f(sv[4 * g + 2]);
      float e3 = __builtin_amdgcn_exp2f(sv[4 * g + 3]);
      ls2 += (f32x2){e0, e1};
      ls2 += (f32x2){e2, e3};
      Pd[2 * g + 0] = cvtpk(e0, e1);
      Pd[2 * g + 1] = cvtpk(e2, e3);
    }
    // pswap(a,b): a.row1 <-> b.row0 =>
    //  Pd[0]' = {lo: own k0k1,        hi: lo-half's k8k9 }  = B dword0
    //  Pd[2]' = {lo: hi-half's k4k5,  hi: own k12k13     }  = B dword2
    pswap(Pd[0], Pd[2]);
    pswap(Pd[1], Pd[3]);
    pswap(Pd[4], Pd[6]);
    pswap(Pd[5], Pd[7]);
    pb0 = mk8(Pd[0], Pd[1], Pd[2], Pd[3]);
    pb1 = mk8(Pd[4], Pd[5], Pd[6], Pd[7]);
  };

  short8 ak0 = *(const short8*)(Kp);
  short8 ak1 = *(const short8*)(Kp + 16);
  short8 av0 = *(const short8*)(Vp);
  short8 av1 = *(const short8*)(Vp + 16);

  for (int i = 0; i < nch; ++i) {
    const size_t kn = (i + 1 < nch) ? (size_t)(i + 1) * 32 : 0;
    short8 nk0 = *(const short8*)(Kp + kn * HD);
    short8 nk1 = *(const short8*)(Kp + kn * HD + 16);
    short8 nv0 = *(const short8*)(Vp + kn);
    short8 nv1 = *(const short8*)(Vp + kn + 16);

    f32x16 sA = __builtin_amdgcn_mfma_f32_32x32x16_bf16(ak0, bqA0, zero16,
                                                        0, 0, 0);
    sA = __builtin_amdgcn_mfma_f32_32x32x16_bf16(ak1, bqA1, sA, 0, 0, 0);
    f32x16 sB = __builtin_amdgcn_mfma_f32_32x32x16_bf16(ak0, bqB0, zero16,
                                                        0, 0, 0);
    sB = __builtin_amdgcn_mfma_f32_32x32x16_bf16(ak1, bqB1, sB, 0, 0, 0);

    short8 pbA0, pbA1, pbB0, pbB1;
    softmax_pack(sA, lsA, pbA0, pbA1);
    softmax_pack(sB, lsB, pbB0, pbB1);

    oA = __builtin_amdgcn_mfma_f32_32x32x16_bf16(av0, pbA0, oA, 0, 0, 0);
    oA = __builtin_amdgcn_mfma_f32_32x32x16_bf16(av1, pbA1, oA, 0, 0, 0);
    oB = __builtin_amdgcn_mfma_f32_32x32x16_bf16(av0, pbB0, oB, 0, 0, 0);
    oB = __builtin_amdgcn_mfma_f32_32x32x16_bf16(av1, pbB1, oB, 0, 0, 0);

    ak0 = nk0; ak1 = nk1; av0 = nv0; av1 = nv1;
  }

  float lsumA = lsA[0] + lsA[1];
  lsumA += __shfl_xor(lsumA, 32);  // full row sum over both halves
  float lsumB = lsB[0] + lsB[1];
  lsumB += __shfl_xor(lsumB, 32);

  // two-stage combine across waves (17 KB LDS), both tiles in parallel
  auto dump = [&](int tl, int sidx, const f32x16& o, float ls) {
#pragma unroll
    for (int r = 0; r < 16; ++r) Cb[tl][sidx][r][lane] = o[r];
    Cb[tl][sidx][16][lane] = ls;
  };
  auto accum = [&](int tl, int sidx, f32x16& o, float& ls) {
#pragma unroll
    for (int r = 0; r < 16; ++r) o[r] += Cb[tl][sidx][r][lane];
    ls += Cb[tl][sidx][16][lane];
  };
  if (wave == 1) { dump(0, 0, oA, lsumA); dump(1, 0, oB, lsumB); }
  if (wave == 3) { dump(0, 1, oA, lsumA); dump(1, 1, oB, lsumB); }
  __syncthreads();
  if (wave == 0) { accum(0, 0, oA, lsumA); accum(1, 0, oB, lsumB); }
  if (wave == 2) { accum(0, 1, oA, lsumA); accum(1, 1, oB, lsumB); }
  __syncthreads();
  if (wave == 2) { dump(0, 0, oA, lsumA); dump(1, 0, oB, lsumB); }
  __syncthreads();
  if (wave == 0) {
    accum(0, 0, oA, lsumA);
    accum(1, 0, oB, lsumB);
    // O^T C-layout: col q = q32, row d = (r&3)+8*(r>>2)+4*lh
    const float invA = 1.f / lsumA;
    short* OpA =
        &Obf[((size_t)bt * NTOK + q0 + q32) * INNER + h * HD + lh * 4];
#pragma unroll
    for (int g = 0; g < 4; ++g) {
      unsigned d0 = cvtpk(oA[4 * g + 0] * invA, oA[4 * g + 1] * invA);
      unsigned d1 = cvtpk(oA[4 * g + 2] * invA, oA[4 * g + 3] * invA);
      *(uint2*)&OpA[8 * g] = make_uint2(d0, d1);
    }
    const float invB = 1.f / lsumB;
    short* OpB =
        &Obf[((size_t)bt * NTOK + q0 + 32 + q32) * INNER + h * HD + lh * 4];
#pragma unroll
    for (int g = 0; g < 4; ++g) {
      unsigned d0 = cvtpk(oB[4 * g + 0] * invB, oB[4 * g + 1] * invB);
      unsigned d1 = cvtpk(oB[4 * g + 2] * invB, oB[4 * g + 3] * invB);
      *(uint2*)&OpB[8 * g] = make_uint2(d0, d1);
    }
  }
}

// ---- output projection (MFMA). grid (25, 4, 8): 64 tok x 64 dout tiles ----
__global__ __launch_bounds__(256) void oproj_mfma(
    const short* __restrict__ Obf, const float* __restrict__ Wo,
    const float* __restrict__ bo, float* __restrict__ out) {
  const int tok0 = blockIdx.x * 64, d0 = blockIdx.y * 64;
  const int bt = blockIdx.z;
  const int t = threadIdx.x, lane = t & 63, w = t >> 6;
  const int quad = lane >> 4, n16 = lane & 15;
  __shared__ short Wos[64 * 36];  // [dout][i] bf16
  f32x4 acc[4];
#pragma unroll
  for (int i = 0; i < 4; ++i) acc[i] = (f32x4){0.f, 0.f, 0.f, 0.f};
  const int tok = tok0 + w * 16 + n16;  // always < 1600

  float wf0[4], wf1[4];
  short8 bfr;
  auto loadWo = [&](int c) {
#pragma unroll
    for (int dp = 0; dp < 4; ++dp) {
      int il = w * 8 + dp * 2;
      wf0[dp] = Wo[(size_t)(c * 32 + il) * QDIM + d0 + lane];
      wf1[dp] = Wo[(size_t)(c * 32 + il + 1) * QDIM + d0 + lane];
    }
  };
  auto loadB = [&](int c) {
    bfr = *(const short8*)&Obf[((size_t)bt * NTOK + tok) * INNER + c * 32 +
                               quad * 8];
  };
  loadWo(0); loadB(0);

  for (int c = 0; c < 4; ++c) {
#pragma unroll
    for (int dp = 0; dp < 4; ++dp)
      *(unsigned*)&Wos[lane * 36 + w * 8 + dp * 2] = cvtpk(wf0[dp], wf1[dp]);
    __syncthreads();
    short8 b0 = bfr;
    if (c < 3) { loadWo(c + 1); loadB(c + 1); }
#pragma unroll
    for (int ag = 0; ag < 4; ++ag) {
      short8 a = ldsfrag(&Wos[(ag * 16 + n16) * 36 + quad * 8]);
      acc[ag] = __builtin_amdgcn_mfma_f32_16x16x32_bf16(a, b0, acc[ag], 0, 0, 0);
    }
    __syncthreads();
  }

#pragma unroll
  for (int ag = 0; ag < 4; ++ag) {
    f32x4 a = acc[ag];
#pragma unroll
    for (int r = 0; r < 4; ++r) {
      int dout = d0 + ag * 16 + quad * 4 + r;
      out[((size_t)bt * QDIM + dout) * NTOK + tok] = a[r] + bo[dout];
    }
  }
}

extern "C" void kernel_launch(void* const* d_in, const int* in_sizes, int n_in,
                              void* d_out, int out_size, void* d_ws,
                              size_t ws_size, hipStream_t stream) {
  const float* query = (const float*)d_in[0];
  const float* key = (const float*)d_in[1];
  const float* value = (const float*)d_in[2];
  const float* Wq = (const float*)d_in[3];
  const float* Wk = (const float*)d_in[4];
  const float* Wv = (const float*)d_in[5];
  const float* Wo = (const float*)d_in[6];
  const float* bo = (const float*)d_in[7];
  float* out = (float*)d_out;

  const size_t arr = (size_t)BT_TOTAL * INNER * NTOK;
  short* Qbf = (short*)d_ws;
  short* Kbf = Qbf + arr;
  short* Vbf = Kbf + arr;
  short* Obf = Vbf + arr;

  proj_fused<<<dim3(25, 3, BT_TOTAL), 256, 0, stream>>>(
      query, Wq, key, Wk, value, Wv, Qbf, Kbf, Vbf);
  attn_mfma<<<dim3(800), 256, 0, stream>>>(Qbf, Kbf, Vbf, Obf);
  oproj_mfma<<<dim3(25, 4, BT_TOTAL), 256, 0, stream>>>(Obf, Wo, bo, out);
}